// Round 10
// baseline (806.199 us; speedup 1.0000x reference)
//
#include <hip/hip_runtime.h>
#include <cstdint>
#include <cstddef>

#define D_MODEL 1024
#define D_FF 4096
#define NTOK 4096
#define LN_EPS 1e-5f

typedef __bf16 bf16x8 __attribute__((ext_vector_type(8)));
typedef float f32x4 __attribute__((ext_vector_type(4)));
typedef unsigned short u16x4 __attribute__((ext_vector_type(4)));
typedef unsigned short u16x8 __attribute__((ext_vector_type(8)));

static __device__ __forceinline__ unsigned short f2bf(float f) {
    union { float f; unsigned u; } v; v.f = f;
    unsigned r = v.u + 0x7fffu + ((v.u >> 16) & 1u);
    return (unsigned short)(r >> 16);
}

static __device__ __forceinline__ float b2f(unsigned short u) {
    union { unsigned u; float f; } v; v.u = (unsigned)u << 16;
    return v.f;
}

// tanh-form GELU as x*sigmoid(2u), log2e pre-folded (proven round 7)
static __device__ __forceinline__ float gelu_fast(float x) {
    float x2 = x * x;
    float a2 = x * __builtin_fmaf(-0.1029432f, x2, -2.3022084f);  // -2u*log2(e)
    float e = __builtin_amdgcn_exp2f(a2);
    return x * __builtin_amdgcn_rcpf(1.0f + e);
}

static __device__ __forceinline__ void gload16(const void* g, void* l) {
    __builtin_amdgcn_global_load_lds(
        (const __attribute__((address_space(1))) void*)g,
        (__attribute__((address_space(3))) void*)l, 16, 0, 0);
}

// padded (256-aligned) prefix offsets of the 4 variable experts in the row slab
static __device__ __forceinline__ void seg_of(const int* cnt, int seg[4], int pc[4]) {
    int o = 2 * NTOK;
    #pragma unroll
    for (int e = 0; e < 4; ++e) {
        int c = cnt[e * 32];
        pc[e] = (c + 255) & ~255;
        seg[e] = o;
        o += pc[e];
    }
}

// ---------------- x: f32 -> bf16 ----------------
__global__ __launch_bounds__(256) void convx_kernel(const float* __restrict__ x,
                                                    unsigned short* __restrict__ xb) {
    int idx = blockIdx.x * 256 + threadIdx.x;   // float4 units
    f32x4 v = *(const f32x4*)&x[(size_t)idx * 4];
    u16x4 b;
    b[0] = f2bf(v[0]); b[1] = f2bf(v[1]); b[2] = f2bf(v[2]); b[3] = f2bf(v[3]);
    *(u16x4*)&xb[(size_t)idx * 4] = b;
}

// ---------------- W [E][K][N] f32 -> Wt [E][N][K] bf16 ----------------
__global__ __launch_bounds__(256) void transpose_kernel(const float* __restrict__ W,
                                                        unsigned short* __restrict__ Wt,
                                                        int K, int N) {
    __shared__ unsigned short t[64][65];
    int k0 = blockIdx.y * 64, n0 = blockIdx.x * 64;
    const float* We = W + (size_t)blockIdx.z * K * N;
    unsigned short* Wte = Wt + (size_t)blockIdx.z * K * N;
    #pragma unroll
    for (int i = 0; i < 4; ++i) {
        int idx = threadIdx.x + i * 256;
        int kr = idx >> 4, c4 = idx & 15;
        f32x4 v = *(const f32x4*)&We[(size_t)(k0 + kr) * N + n0 + c4 * 4];
        #pragma unroll
        for (int j = 0; j < 4; ++j) t[c4 * 4 + j][kr] = f2bf(v[j]);
    }
    __syncthreads();
    #pragma unroll
    for (int i = 0; i < 2; ++i) {
        int idx = threadIdx.x + i * 256;
        int nr = idx >> 3, ck = idx & 7;
        u16x8 w;
        #pragma unroll
        for (int j = 0; j < 8; ++j) w[j] = t[nr][ck * 8 + j];
        *(u16x8*)&Wte[(size_t)(n0 + nr) * K + k0 + ck * 8] = w;
    }
}

// ---------------- router: logits + top-2 + compaction ----------------
__global__ __launch_bounds__(256) void router_kernel(
        const float* __restrict__ x, const float* __restrict__ rW,
        float* __restrict__ logits, int* __restrict__ selpk,
        int* __restrict__ slotpk, int* __restrict__ cnt, int* __restrict__ list) {
    __shared__ int se[8];
    __shared__ int sslot[8];
    int wid = threadIdx.x >> 6, lane = threadIdx.x & 63;
    int t = blockIdx.x * 4 + wid;
    const float* xr = x + (size_t)t * D_MODEL;
    float a0 = 0.f, a1 = 0.f, a2 = 0.f, a3 = 0.f;
    for (int d = lane; d < D_MODEL; d += 64) {
        float xv = xr[d];
        const float* w = rW + d * 4;
        a0 += xv * w[0]; a1 += xv * w[1]; a2 += xv * w[2]; a3 += xv * w[3];
    }
    #pragma unroll
    for (int off = 32; off; off >>= 1) {
        a0 += __shfl_xor(a0, off); a1 += __shfl_xor(a1, off);
        a2 += __shfl_xor(a2, off); a3 += __shfl_xor(a3, off);
    }
    if (lane == 0) {
        float l[4] = {a0, a1, a2, a3};
        logits[t * 4 + 0] = a0; logits[t * 4 + 1] = a1;
        logits[t * 4 + 2] = a2; logits[t * 4 + 3] = a3;
        int e0 = 0; float b = l[0];
        #pragma unroll
        for (int e = 1; e < 4; ++e) if (l[e] > b) { b = l[e]; e0 = e; }
        int e1 = -1; float b2 = -1e30f;
        #pragma unroll
        for (int e = 0; e < 4; ++e) {
            if (e == e0) continue;
            if (l[e] > b2) { b2 = l[e]; e1 = e; }
        }
        se[wid * 2] = e0; se[wid * 2 + 1] = e1;
    }
    __syncthreads();
    if (threadIdx.x == 0) {
        int cnts[4] = {0, 0, 0, 0}, base[4];
        #pragma unroll
        for (int k = 0; k < 8; ++k) cnts[se[k]]++;
        #pragma unroll
        for (int e = 0; e < 4; ++e)
            if (cnts[e]) base[e] = atomicAdd(&cnt[e * 32], cnts[e]);
        int run[4] = {0, 0, 0, 0};
        #pragma unroll
        for (int k = 0; k < 8; ++k) {
            int e = se[k];
            int s = base[e] + run[e]++;
            sslot[k] = s;
            list[e * NTOK + s] = blockIdx.x * 4 + (k >> 1);
        }
    }
    __syncthreads();
    if (lane == 0) {
        selpk[t] = se[wid * 2] | (se[wid * 2 + 1] << 8);
        slotpk[t] = sslot[wid * 2] | (sslot[wid * 2 + 1] << 16);
    }
}

// ------- 4-wave, per-wave 128x64 2-barrier GEMM (round-9 core, fat waves) -----
// Block = 256 threads = WAVES_M x WAVES_N waves; per-wave C = (BM/WAVES_M) x
// (BN/WAVES_N) = 128x64 -> acc[8][4], MR*NR = 32 MFMA per kk from 12 ds_reads
// (1.33x better FLOP/LDS-byte than 64x64 waves). 48 KiB LDS; VGPR ~130-220 ->
// 2 independent blocks/CU whose barriers interleave (TLP hides vmcnt(0) drain).
// No min-occupancy launch_bounds (round-8 spill lesson).
// Quad-XCD swizzle (round 9, bijective for nwg%32==0).
template<int GELU, int BM, int BN, int WAVES_M, int WAVES_N, int GX, int GY>
__global__ __launch_bounds__(256) void gemm_kernel(
        const unsigned short* __restrict__ A, const unsigned short* __restrict__ B,
        const float* __restrict__ bias, int bias_stride, int ldo,
        unsigned short* __restrict__ out,
        const int* __restrict__ cnt, const int* __restrict__ list, int K) {
    constexpr int NA = BM / 32, NB = BN / 32;      // staging rounds (32 rows/round)
    constexpr int WM = BM / WAVES_M, WN = BN / WAVES_N;  // 128, 64
    constexpr int MR = WM / 16, NR = WN / 16;      // 8, 4
    __shared__ unsigned short As[BM * 64];
    __shared__ unsigned short Bs[BN * 64];

    // balanced quad-XCD swizzle (nwg = GX*GY*6, multiple of 32 for both passes)
    const int D = blockIdx.x + GX * (blockIdx.y + GY * blockIdx.z);
    const int tq = D >> 3;
    const int W = ((D & 7) << 2) + ((tq >> 2) << 5) + (tq & 3);
    const int bx = W % GX;
    const int rem = W / GX;
    const int by = rem % GY;
    const int e  = rem / GY;

    const int tid = threadIdx.x, lane = tid & 63, w = tid >> 6;
    int ecnt = NTOK, rowbase;
    if (e < 2) {
        rowbase = e * NTOK + by * BM;
    } else {
        int seg[4], pc[4];
        seg_of(cnt, seg, pc);
        int ev = e - 2;
        ecnt = cnt[ev * 32];
        if (by * BM >= pc[ev]) return;   // before any barrier
        rowbase = seg[ev] + by * BM;
    }
    const int n0 = bx * BN;
    const unsigned short* Be = B + (size_t)e * (D_FF * D_MODEL);

    // per-thread staging sources: round i covers rows i*32 + w*8 + (lane>>3);
    // source piece (lane&7)^(row&7) (pre-swizzled source + swizzled read)
    const unsigned short* asrc[NA];
    const unsigned short* bsrc[NB];
    #pragma unroll
    for (int i = 0; i < NA; ++i) {
        int row = i * 32 + w * 8 + (lane >> 3);
        int kc = lane & 7;
        size_t arow;
        if (GELU) {
            int s = by * BM + row;
            if (e < 2) arow = (size_t)s;
            else       arow = (size_t)((s < ecnt) ? list[(e - 2) * NTOK + s] : 0);
        } else {
            arow = (size_t)(rowbase + row);
        }
        asrc[i] = A + arow * K + ((kc ^ (row & 7)) << 3);
    }
    #pragma unroll
    for (int i = 0; i < NB; ++i) {
        int row = i * 32 + w * 8 + (lane >> 3);
        int kc = lane & 7;
        bsrc[i] = Be + (size_t)(n0 + row) * K + ((kc ^ (row & 7)) << 3);
    }

    const int wm = (w / WAVES_N) * WM, wn = (w % WAVES_N) * WN;
    const int rl = lane & 15, kq = lane >> 4;

    // bias folded into accumulator init (column-only => all 4 C regs equal)
    float bv[NR];
    #pragma unroll
    for (int ni = 0; ni < NR; ++ni)
        bv[ni] = bias[(size_t)e * bias_stride + n0 + wn + ni * 16 + rl];

    f32x4 acc[MR][NR];
    #pragma unroll
    for (int mi = 0; mi < MR; ++mi)
        #pragma unroll
        for (int ni = 0; ni < NR; ++ni) acc[mi][ni] = (f32x4)(bv[ni]);

    for (int kb = 0; kb < K; kb += 64) {
        #pragma unroll
        for (int i = 0; i < NA; ++i)
            gload16(asrc[i] + kb, &As[i * 2048 + w * 512]);
        #pragma unroll
        for (int i = 0; i < NB; ++i)
            gload16(bsrc[i] + kb, &Bs[i * 2048 + w * 512]);
        asm volatile("s_waitcnt vmcnt(0)" ::: "memory");
        __syncthreads();
        #pragma unroll
        for (int kk = 0; kk < 2; ++kk) {
            int kof = kk * 32 + kq * 8;
            bf16x8 b[NR];
            #pragma unroll
            for (int ni = 0; ni < NR; ++ni) {
                int r = wn + ni * 16 + rl;
                b[ni] = *(const bf16x8*)&Bs[r * 64 + (kof ^ ((r & 7) << 3))];
            }
            #pragma unroll
            for (int mh = 0; mh < MR / 4; ++mh) {
                bf16x8 a[4];
                #pragma unroll
                for (int mi = 0; mi < 4; ++mi) {
                    int r = wm + (mh * 4 + mi) * 16 + rl;
                    a[mi] = *(const bf16x8*)&As[r * 64 + (kof ^ ((r & 7) << 3))];
                }
                #pragma unroll
                for (int mi = 0; mi < 4; ++mi)
                    #pragma unroll
                    for (int ni = 0; ni < NR; ++ni)
                        acc[mh * 4 + mi][ni] = __builtin_amdgcn_mfma_f32_16x16x32_bf16(
                            a[mi], b[ni], acc[mh * 4 + mi][ni], 0, 0, 0);
            }
        }
        __syncthreads();
    }

    // epilogue: (gelu) + packed bf16 convert + store
    #pragma unroll
    for (int ni = 0; ni < NR; ++ni) {
        int c = n0 + wn + ni * 16 + rl;
        #pragma unroll
        for (int mi = 0; mi < MR; ++mi) {
            #pragma unroll
            for (int jp = 0; jp < 2; ++jp) {
                float g0 = acc[mi][ni][jp * 2 + 0];
                float g1 = acc[mi][ni][jp * 2 + 1];
                if (GELU) { g0 = gelu_fast(g0); g1 = gelu_fast(g1); }
                unsigned pk;
                asm("v_cvt_pk_bf16_f32 %0, %1, %2" : "=v"(pk) : "v"(g0), "v"(g1));
                int r = wm + mi * 16 + kq * 4 + jp * 2;
                unsigned short* p = out + (size_t)(rowbase + r) * ldo + c;
                p[0]   = (unsigned short)pk;
                p[ldo] = (unsigned short)(pk >> 16);
            }
        }
    }
}

// ---------------- pass3: gather 4 bf16 rows, /4, LayerNorm ----------------
__global__ __launch_bounds__(256) void pass3_kernel(
        const unsigned short* __restrict__ oslab, const int* __restrict__ selpk,
        const int* __restrict__ slotpk, const int* __restrict__ cnt,
        const float* __restrict__ gamma, const float* __restrict__ beta,
        float* __restrict__ out) {
    int t = blockIdx.x;
    int seg[4], pc[4];
    seg_of(cnt, seg, pc);
    int sp = selpk[t], sl = slotpk[t];
    int e0 = sp & 0xff, e1 = (sp >> 8) & 0xff;
    int s0 = sl & 0xffff, s1 = (sl >> 16) & 0xffff;
    const unsigned short* p0 = oslab + (size_t)t * D_MODEL;
    const unsigned short* p1 = oslab + (size_t)(NTOK + t) * D_MODEL;
    const unsigned short* p2 = oslab + (size_t)(seg[e0] + s0) * D_MODEL;
    const unsigned short* p3 = oslab + (size_t)(seg[e1] + s1) * D_MODEL;
    float c[4];
    float sum = 0.f, sq = 0.f;
    #pragma unroll
    for (int i = 0; i < 4; ++i) {
        int d = threadIdx.x + i * 256;
        float v = (b2f(p0[d]) + b2f(p1[d]) + b2f(p2[d]) + b2f(p3[d])) * 0.25f;
        c[i] = v; sum += v; sq += v * v;
    }
    #pragma unroll
    for (int off = 32; off; off >>= 1) {
        sum += __shfl_xor(sum, off);
        sq  += __shfl_xor(sq, off);
    }
    __shared__ float red[8];
    int lane = threadIdx.x & 63, wid = threadIdx.x >> 6;
    if (lane == 0) { red[wid] = sum; red[4 + wid] = sq; }
    __syncthreads();
    sum = red[0] + red[1] + red[2] + red[3];
    sq  = red[4] + red[5] + red[6] + red[7];
    float mean = sum * (1.0f / 1024.0f);
    float var = sq * (1.0f / 1024.0f) - mean * mean;
    float inv = rsqrtf(var + LN_EPS);
    #pragma unroll
    for (int i = 0; i < 4; ++i) {
        int d = threadIdx.x + i * 256;
        out[(size_t)t * D_MODEL + d] = (c[i] - mean) * inv * gamma[d] + beta[d];
    }
}

extern "C" void kernel_launch(void* const* d_in, const int* in_sizes, int n_in,
                              void* d_out, int out_size, void* d_ws, size_t ws_size,
                              hipStream_t stream) {
    const float* x   = (const float*)d_in[0];
    const float* rW  = (const float*)d_in[1];
    const float* W1  = (const float*)d_in[2];
    const float* b1  = (const float*)d_in[3];
    const float* W2  = (const float*)d_in[4];
    const float* b2  = (const float*)d_in[5];
    const float* gam = (const float*)d_in[6];
    const float* bet = (const float*)d_in[7];
    float* out = (float*)d_out;
    float* logits = out + (size_t)NTOK * D_MODEL;

    char* ws = (char*)d_ws;
    int* cnt    = (int*)ws;                     // 4 counters, 128B apart
    int* selpk  = (int*)(ws + 0x1000);
    int* slotpk = (int*)(ws + 0x6000);
    int* list   = (int*)(ws + 0xB000);          // 4*4096*4 = 64KB
    unsigned short* xb    = (unsigned short*)(ws + 0x20000);    // 8 MiB
    unsigned short* W1t   = (unsigned short*)(ws + 0x820000);   // 48 MiB
    unsigned short* W2t   = (unsigned short*)(ws + 0x3820000);  // 48 MiB
    unsigned short* oslab = (unsigned short*)(ws + 0x6820000);  // 17408*1024*2 = 34 MiB
    unsigned short* h     = (unsigned short*)(ws + 0x8A20000);  // 17408*4096*2 = 136 MiB
    // total ≈ 287.4 MB (proven available)

    convx_kernel<<<NTOK * D_MODEL / 4 / 256, 256, 0, stream>>>(x, xb);
    transpose_kernel<<<dim3(D_FF / 64, D_MODEL / 64, 6), 256, 0, stream>>>(W1, W1t, D_MODEL, D_FF);
    transpose_kernel<<<dim3(D_MODEL / 64, D_FF / 64, 6), 256, 0, stream>>>(W2, W2t, D_FF, D_MODEL);
    hipMemsetAsync(cnt, 0, 512, stream);
    router_kernel<<<NTOK / 4, 256, 0, stream>>>(x, rW, logits, selpk, slotpk, cnt, list);

    // pass1: h = gelu(x @ W1^T + b1)   BM=256, BN=128, waves 2x2 (128x64 each)
    // grid (32, 16, 6) => nwg 3072 (mult of 32)
    gemm_kernel<1, 256, 128, 2, 2, 32, 16><<<dim3(32, 16, 6), 256, 0, stream>>>(
        xb, W1t, b1, D_FF, D_FF, h, cnt, list, D_MODEL);
    // pass2: oslab = h @ W2^T + b2     BM=128, BN=256, waves 1x4 (128x64 each)
    // grid (4, 32, 6) => nwg 768 (mult of 32)
    gemm_kernel<0, 128, 256, 1, 4, 4, 32><<<dim3(4, 32, 6), 256, 0, stream>>>(
        h, W2t, b2, D_MODEL, D_MODEL, oslab, cnt, list, D_FF);

    pass3_kernel<<<NTOK, 256, 0, stream>>>(oslab, selpk, slotpk, cnt, gam, bet, out);
}

// Round 11
// 549.269 us; speedup vs baseline: 1.4678x; 1.4678x over previous
//
#include <hip/hip_runtime.h>
#include <cstdint>
#include <cstddef>

#define D_MODEL 1024
#define D_FF 4096
#define NTOK 4096
#define LN_EPS 1e-5f

typedef __bf16 bf16x8 __attribute__((ext_vector_type(8)));
typedef float f32x4 __attribute__((ext_vector_type(4)));
typedef unsigned short u16x4 __attribute__((ext_vector_type(4)));
typedef unsigned short u16x8 __attribute__((ext_vector_type(8)));

static __device__ __forceinline__ unsigned short f2bf(float f) {
    union { float f; unsigned u; } v; v.f = f;
    unsigned r = v.u + 0x7fffu + ((v.u >> 16) & 1u);
    return (unsigned short)(r >> 16);
}

static __device__ __forceinline__ float b2f(unsigned short u) {
    union { unsigned u; float f; } v; v.u = (unsigned)u << 16;
    return v.f;
}

// tanh-form GELU as x*sigmoid(2u), log2e pre-folded (proven round 7)
static __device__ __forceinline__ float gelu_fast(float x) {
    float x2 = x * x;
    float a2 = x * __builtin_fmaf(-0.1029432f, x2, -2.3022084f);  // -2u*log2(e)
    float e = __builtin_amdgcn_exp2f(a2);
    return x * __builtin_amdgcn_rcpf(1.0f + e);
}

static __device__ __forceinline__ void gload16(const void* g, void* l) {
    __builtin_amdgcn_global_load_lds(
        (const __attribute__((address_space(1))) void*)g,
        (__attribute__((address_space(3))) void*)l, 16, 0, 0);
}

// padded (256-aligned) prefix offsets of the 4 variable experts in the row slab
static __device__ __forceinline__ void seg_of(const int* cnt, int seg[4], int pc[4]) {
    int o = 2 * NTOK;
    #pragma unroll
    for (int e = 0; e < 4; ++e) {
        int c = cnt[e * 32];
        pc[e] = (c + 255) & ~255;
        seg[e] = o;
        o += pc[e];
    }
}

// ---------------- W [E][K][N] f32 -> Wt [E][N][K] bf16 ----------------
__global__ __launch_bounds__(256) void transpose_kernel(const float* __restrict__ W,
                                                        unsigned short* __restrict__ Wt,
                                                        int K, int N) {
    __shared__ unsigned short t[64][65];
    int k0 = blockIdx.y * 64, n0 = blockIdx.x * 64;
    const float* We = W + (size_t)blockIdx.z * K * N;
    unsigned short* Wte = Wt + (size_t)blockIdx.z * K * N;
    #pragma unroll
    for (int i = 0; i < 4; ++i) {
        int idx = threadIdx.x + i * 256;
        int kr = idx >> 4, c4 = idx & 15;
        f32x4 v = *(const f32x4*)&We[(size_t)(k0 + kr) * N + n0 + c4 * 4];
        #pragma unroll
        for (int j = 0; j < 4; ++j) t[c4 * 4 + j][kr] = f2bf(v[j]);
    }
    __syncthreads();
    #pragma unroll
    for (int i = 0; i < 2; ++i) {
        int idx = threadIdx.x + i * 256;
        int nr = idx >> 3, ck = idx & 7;
        u16x8 w;
        #pragma unroll
        for (int j = 0; j < 8; ++j) w[j] = t[nr][ck * 8 + j];
        *(u16x8*)&Wte[(size_t)(n0 + nr) * K + k0 + ck * 8] = w;
    }
}

// ------- router (fused x->bf16 convert): logits + top-2 + compaction + xb -----
__global__ __launch_bounds__(256) void router_kernel(
        const float* __restrict__ x, const float* __restrict__ rW,
        float* __restrict__ logits, int* __restrict__ selpk,
        int* __restrict__ slotpk, int* __restrict__ cnt, int* __restrict__ list,
        unsigned short* __restrict__ xb) {
    __shared__ int se[8];
    __shared__ int sslot[8];
    int wid = threadIdx.x >> 6, lane = threadIdx.x & 63;
    int t = blockIdx.x * 4 + wid;
    const float* xr = x + (size_t)t * D_MODEL;
    unsigned short* xbr = xb + (size_t)t * D_MODEL;
    float a0 = 0.f, a1 = 0.f, a2 = 0.f, a3 = 0.f;
    #pragma unroll
    for (int i = 0; i < 4; ++i) {
        int d4 = lane + i * 64;                 // float4 index within row
        f32x4 xv = *(const f32x4*)&xr[d4 * 4];
        u16x4 bo;
        #pragma unroll
        for (int j = 0; j < 4; ++j) {
            float xj = xv[j];
            f32x4 wv = *(const f32x4*)&rW[(d4 * 4 + j) * 4];
            a0 = __builtin_fmaf(xj, wv[0], a0);
            a1 = __builtin_fmaf(xj, wv[1], a1);
            a2 = __builtin_fmaf(xj, wv[2], a2);
            a3 = __builtin_fmaf(xj, wv[3], a3);
            bo[j] = f2bf(xj);
        }
        *(u16x4*)&xbr[d4 * 4] = bo;
    }
    #pragma unroll
    for (int off = 32; off; off >>= 1) {
        a0 += __shfl_xor(a0, off); a1 += __shfl_xor(a1, off);
        a2 += __shfl_xor(a2, off); a3 += __shfl_xor(a3, off);
    }
    if (lane == 0) {
        float l[4] = {a0, a1, a2, a3};
        logits[t * 4 + 0] = a0; logits[t * 4 + 1] = a1;
        logits[t * 4 + 2] = a2; logits[t * 4 + 3] = a3;
        int e0 = 0; float b = l[0];
        #pragma unroll
        for (int e = 1; e < 4; ++e) if (l[e] > b) { b = l[e]; e0 = e; }
        int e1 = -1; float b2 = -1e30f;
        #pragma unroll
        for (int e = 0; e < 4; ++e) {
            if (e == e0) continue;
            if (l[e] > b2) { b2 = l[e]; e1 = e; }
        }
        se[wid * 2] = e0; se[wid * 2 + 1] = e1;
    }
    __syncthreads();
    if (threadIdx.x == 0) {
        int cnts[4] = {0, 0, 0, 0}, base[4];
        #pragma unroll
        for (int k = 0; k < 8; ++k) cnts[se[k]]++;
        #pragma unroll
        for (int e = 0; e < 4; ++e)
            if (cnts[e]) base[e] = atomicAdd(&cnt[e * 32], cnts[e]);
        int run[4] = {0, 0, 0, 0};
        #pragma unroll
        for (int k = 0; k < 8; ++k) {
            int e = se[k];
            int s = base[e] + run[e]++;
            sslot[k] = s;
            list[e * NTOK + s] = blockIdx.x * 4 + (k >> 1);
        }
    }
    __syncthreads();
    if (lane == 0) {
        selpk[t] = se[wid * 2] | (se[wid * 2 + 1] << 8);
        slotpk[t] = sslot[wid * 2] | (sslot[wid * 2 + 1] << 16);
    }
}

// ------- 128x128 4-wave GEMM, catalog minimum-2-phase double buffer ----------
// r7 proven core (involution swizzle, bias-fold, cvt_pk epilogue) + T3-min:
//   STAGE(t+1) issued BEFORE compute(t); vmcnt(0) drained AFTER the MFMAs ->
//   HBM latency hides under the compute phase. One barrier per tile.
// LDS 2 x 32KB = 64KB -> 2 blocks/CU (matches r7's measured residency), so
// intra-block overlap is added without losing cross-block TLP.
template<int GELU>
__global__ __launch_bounds__(256) void gemm_kernel(
        const unsigned short* __restrict__ A, const unsigned short* __restrict__ B,
        const float* __restrict__ bias, int bias_stride, int ldo,
        unsigned short* __restrict__ out,
        const int* __restrict__ cnt, const int* __restrict__ list, int K) {
    __shared__ unsigned short As[2][128 * 64];
    __shared__ unsigned short Bs[2][128 * 64];
    const int e = blockIdx.z;
    const int tid = threadIdx.x, lane = tid & 63, wid = tid >> 6;
    int ecnt = NTOK, rowbase;
    if (e < 2) {
        rowbase = e * NTOK + blockIdx.y * 128;
    } else {
        int seg[4], pc[4];
        seg_of(cnt, seg, pc);
        int ev = e - 2;
        ecnt = cnt[ev * 32];
        if ((int)blockIdx.y * 128 >= pc[ev]) return;   // before any barrier
        rowbase = seg[ev] + blockIdx.y * 128;
    }
    const int n0 = blockIdx.x * 128;
    const unsigned short* Be = B + (size_t)e * (D_FF * D_MODEL);

    // per-thread staging sources (pre-swizzled source piece, linear LDS dest)
    const unsigned short* asrc[4];
    const unsigned short* bsrc[4];
    #pragma unroll
    for (int j = 0; j < 4; ++j) {
        int row = (wid * 4 + j) * 8 + (lane >> 3);
        int kc = lane & 7;
        size_t arow;
        if (GELU) {
            int s = blockIdx.y * 128 + row;
            if (e < 2) arow = (size_t)s;
            else       arow = (size_t)((s < ecnt) ? list[(e - 2) * NTOK + s] : 0);
        } else {
            arow = (size_t)(rowbase + row);
        }
        asrc[j] = A + arow * K + ((kc ^ (row & 7)) << 3);
        bsrc[j] = Be + (size_t)(n0 + row) * K + ((kc ^ (row & 7)) << 3);
    }
    const int wm = (wid >> 1) * 64, wn = (wid & 1) * 64;
    const int rl = lane & 15, kq = lane >> 4;

    // bias folded into accumulator init (column-only => all 4 C regs equal)
    float bv[4];
    #pragma unroll
    for (int ni = 0; ni < 4; ++ni)
        bv[ni] = bias[(size_t)e * bias_stride + n0 + wn + ni * 16 + rl];

    f32x4 acc[4][4];
    #pragma unroll
    for (int mi = 0; mi < 4; ++mi)
        #pragma unroll
        for (int ni = 0; ni < 4; ++ni) acc[mi][ni] = (f32x4)(bv[ni]);

    const int nt = K / 64;

    #define STAGE(bf, t)                                                        \
        {                                                                       \
            _Pragma("unroll")                                                   \
            for (int j_ = 0; j_ < 4; ++j_) {                                    \
                gload16(asrc[j_] + (t) * 64, &As[bf][(wid * 4 + j_) * 512]);    \
                gload16(bsrc[j_] + (t) * 64, &Bs[bf][(wid * 4 + j_) * 512]);    \
            }                                                                   \
        }

    // prologue: tile 0 staged with a full drain (no compute to hide it under)
    STAGE(0, 0);
    asm volatile("s_waitcnt vmcnt(0)" ::: "memory");
    __syncthreads();

    for (int t = 0; t < nt; ++t) {
        const int cur = t & 1;
        if (t + 1 < nt) STAGE(cur ^ 1, t + 1);   // issue BEFORE compute
        #pragma unroll
        for (int kk = 0; kk < 2; ++kk) {
            int kof = kk * 32 + kq * 8;
            bf16x8 a[4], b[4];
            #pragma unroll
            for (int mi = 0; mi < 4; ++mi) {
                int r = wm + mi * 16 + rl;
                a[mi] = *(const bf16x8*)&As[cur][r * 64 + (kof ^ ((r & 7) << 3))];
            }
            #pragma unroll
            for (int ni = 0; ni < 4; ++ni) {
                int r = wn + ni * 16 + rl;
                b[ni] = *(const bf16x8*)&Bs[cur][r * 64 + (kof ^ ((r & 7) << 3))];
            }
            #pragma unroll
            for (int mi = 0; mi < 4; ++mi)
                #pragma unroll
                for (int ni = 0; ni < 4; ++ni)
                    acc[mi][ni] = __builtin_amdgcn_mfma_f32_16x16x32_bf16(
                        a[mi], b[ni], acc[mi][ni], 0, 0, 0);
        }
        if (t + 1 < nt) {
            asm volatile("s_waitcnt vmcnt(0)" ::: "memory");  // arrived under MFMA
            __syncthreads();
        }
    }
    #undef STAGE

    // epilogue: (gelu) + packed bf16 convert + store
    #pragma unroll
    for (int ni = 0; ni < 4; ++ni) {
        int c = n0 + wn + ni * 16 + rl;
        #pragma unroll
        for (int mi = 0; mi < 4; ++mi) {
            #pragma unroll
            for (int jp = 0; jp < 2; ++jp) {
                float g0 = acc[mi][ni][jp * 2 + 0];
                float g1 = acc[mi][ni][jp * 2 + 1];
                if (GELU) { g0 = gelu_fast(g0); g1 = gelu_fast(g1); }
                unsigned pk;
                asm("v_cvt_pk_bf16_f32 %0, %1, %2" : "=v"(pk) : "v"(g0), "v"(g1));
                int r = wm + mi * 16 + kq * 4 + jp * 2;
                unsigned short* p = out + (size_t)(rowbase + r) * ldo + c;
                p[0]   = (unsigned short)pk;
                p[ldo] = (unsigned short)(pk >> 16);
            }
        }
    }
}

// ---------------- pass3: gather 4 bf16 rows, /4, LayerNorm ----------------
__global__ __launch_bounds__(256) void pass3_kernel(
        const unsigned short* __restrict__ oslab, const int* __restrict__ selpk,
        const int* __restrict__ slotpk, const int* __restrict__ cnt,
        const float* __restrict__ gamma, const float* __restrict__ beta,
        float* __restrict__ out) {
    int t = blockIdx.x;
    int seg[4], pc[4];
    seg_of(cnt, seg, pc);
    int sp = selpk[t], sl = slotpk[t];
    int e0 = sp & 0xff, e1 = (sp >> 8) & 0xff;
    int s0 = sl & 0xffff, s1 = (sl >> 16) & 0xffff;
    const unsigned short* p0 = oslab + (size_t)t * D_MODEL;
    const unsigned short* p1 = oslab + (size_t)(NTOK + t) * D_MODEL;
    const unsigned short* p2 = oslab + (size_t)(seg[e0] + s0) * D_MODEL;
    const unsigned short* p3 = oslab + (size_t)(seg[e1] + s1) * D_MODEL;
    float c[4];
    float sum = 0.f, sq = 0.f;
    #pragma unroll
    for (int i = 0; i < 4; ++i) {
        int d = threadIdx.x + i * 256;
        float v = (b2f(p0[d]) + b2f(p1[d]) + b2f(p2[d]) + b2f(p3[d])) * 0.25f;
        c[i] = v; sum += v; sq += v * v;
    }
    #pragma unroll
    for (int off = 32; off; off >>= 1) {
        sum += __shfl_xor(sum, off);
        sq  += __shfl_xor(sq, off);
    }
    __shared__ float red[8];
    int lane = threadIdx.x & 63, wid = threadIdx.x >> 6;
    if (lane == 0) { red[wid] = sum; red[4 + wid] = sq; }
    __syncthreads();
    sum = red[0] + red[1] + red[2] + red[3];
    sq  = red[4] + red[5] + red[6] + red[7];
    float mean = sum * (1.0f / 1024.0f);
    float var = sq * (1.0f / 1024.0f) - mean * mean;
    float inv = rsqrtf(var + LN_EPS);
    #pragma unroll
    for (int i = 0; i < 4; ++i) {
        int d = threadIdx.x + i * 256;
        out[(size_t)t * D_MODEL + d] = (c[i] - mean) * inv * gamma[d] + beta[d];
    }
}

extern "C" void kernel_launch(void* const* d_in, const int* in_sizes, int n_in,
                              void* d_out, int out_size, void* d_ws, size_t ws_size,
                              hipStream_t stream) {
    const float* x   = (const float*)d_in[0];
    const float* rW  = (const float*)d_in[1];
    const float* W1  = (const float*)d_in[2];
    const float* b1  = (const float*)d_in[3];
    const float* W2  = (const float*)d_in[4];
    const float* b2  = (const float*)d_in[5];
    const float* gam = (const float*)d_in[6];
    const float* bet = (const float*)d_in[7];
    float* out = (float*)d_out;
    float* logits = out + (size_t)NTOK * D_MODEL;

    char* ws = (char*)d_ws;
    int* cnt    = (int*)ws;                     // 4 counters, 128B apart
    int* selpk  = (int*)(ws + 0x1000);
    int* slotpk = (int*)(ws + 0x6000);
    int* list   = (int*)(ws + 0xB000);          // 4*4096*4 = 64KB
    unsigned short* xb    = (unsigned short*)(ws + 0x20000);    // 8 MiB
    unsigned short* W1t   = (unsigned short*)(ws + 0x820000);   // 48 MiB
    unsigned short* W2t   = (unsigned short*)(ws + 0x3820000);  // 48 MiB
    unsigned short* oslab = (unsigned short*)(ws + 0x6820000);  // 17408*1024*2 = 34 MiB
    unsigned short* h     = (unsigned short*)(ws + 0x8A20000);  // 17408*4096*2 = 136 MiB
    // total ≈ 287.4 MB (proven available)

    hipMemsetAsync(cnt, 0, 512, stream);
    router_kernel<<<NTOK / 4, 256, 0, stream>>>(x, rW, logits, selpk, slotpk, cnt, list, xb);
    transpose_kernel<<<dim3(D_FF / 64, D_MODEL / 64, 6), 256, 0, stream>>>(W1, W1t, D_MODEL, D_FF);
    transpose_kernel<<<dim3(D_MODEL / 64, D_FF / 64, 6), 256, 0, stream>>>(W2, W2t, D_FF, D_MODEL);

    // pass1: h = gelu(x @ W1^T + b1)   (M = slab rows, N = 4096, K = 1024)
    gemm_kernel<1><<<dim3(D_FF / 128, 32, 6), 256, 0, stream>>>(
        xb, W1t, b1, D_FF, D_FF, h, cnt, list, D_MODEL);
    // pass2: oslab = h @ W2^T + b2     (M = slab rows, N = 1024, K = 4096)
    gemm_kernel<0><<<dim3(D_MODEL / 128, 32, 6), 256, 0, stream>>>(
        h, W2t, b2, D_MODEL, D_MODEL, oslab, cnt, list, D_FF);

    pass3_kernel<<<NTOK, 256, 0, stream>>>(oslab, selpk, slotpk, cnt, gam, bet, out);
}

// Round 12
// 460.912 us; speedup vs baseline: 1.7491x; 1.1917x over previous
//
#include <hip/hip_runtime.h>
#include <cstdint>
#include <cstddef>

#define D_MODEL 1024
#define D_FF 4096
#define NTOK 4096
#define LN_EPS 1e-5f

typedef __bf16 bf16x8 __attribute__((ext_vector_type(8)));
typedef float f32x4 __attribute__((ext_vector_type(4)));
typedef unsigned short u16x4 __attribute__((ext_vector_type(4)));
typedef unsigned short u16x8 __attribute__((ext_vector_type(8)));

static __device__ __forceinline__ unsigned short f2bf(float f) {
    union { float f; unsigned u; } v; v.f = f;
    unsigned r = v.u + 0x7fffu + ((v.u >> 16) & 1u);
    return (unsigned short)(r >> 16);
}

static __device__ __forceinline__ float b2f(unsigned short u) {
    union { unsigned u; float f; } v; v.u = (unsigned)u << 16;
    return v.f;
}

// tanh-form GELU as x*sigmoid(2u), log2e pre-folded (proven round 7)
static __device__ __forceinline__ float gelu_fast(float x) {
    float x2 = x * x;
    float a2 = x * __builtin_fmaf(-0.1029432f, x2, -2.3022084f);  // -2u*log2(e)
    float e = __builtin_amdgcn_exp2f(a2);
    return x * __builtin_amdgcn_rcpf(1.0f + e);
}

static __device__ __forceinline__ void gload16(const void* g, void* l) {
    __builtin_amdgcn_global_load_lds(
        (const __attribute__((address_space(1))) void*)g,
        (__attribute__((address_space(3))) void*)l, 16, 0, 0);
}

// padded (256-aligned) prefix offsets of the 4 variable experts in the row slab
static __device__ __forceinline__ void seg_of(const int* cnt, int seg[4], int pc[4]) {
    int o = 2 * NTOK;
    #pragma unroll
    for (int e = 0; e < 4; ++e) {
        int c = cnt[e * 32];
        pc[e] = (c + 255) & ~255;
        seg[e] = o;
        o += pc[e];
    }
}

// ---------------- W [E][K][N] f32 -> Wt [E][N][K] bf16 ----------------
__global__ __launch_bounds__(256) void transpose_kernel(const float* __restrict__ W,
                                                        unsigned short* __restrict__ Wt,
                                                        int K, int N) {
    __shared__ unsigned short t[64][65];
    int k0 = blockIdx.y * 64, n0 = blockIdx.x * 64;
    const float* We = W + (size_t)blockIdx.z * K * N;
    unsigned short* Wte = Wt + (size_t)blockIdx.z * K * N;
    #pragma unroll
    for (int i = 0; i < 4; ++i) {
        int idx = threadIdx.x + i * 256;
        int kr = idx >> 4, c4 = idx & 15;
        f32x4 v = *(const f32x4*)&We[(size_t)(k0 + kr) * N + n0 + c4 * 4];
        #pragma unroll
        for (int j = 0; j < 4; ++j) t[c4 * 4 + j][kr] = f2bf(v[j]);
    }
    __syncthreads();
    #pragma unroll
    for (int i = 0; i < 2; ++i) {
        int idx = threadIdx.x + i * 256;
        int nr = idx >> 3, ck = idx & 7;
        u16x8 w;
        #pragma unroll
        for (int j = 0; j < 8; ++j) w[j] = t[nr][ck * 8 + j];
        *(u16x8*)&Wte[(size_t)(n0 + nr) * K + k0 + ck * 8] = w;
    }
}

// ------- router (fused x->bf16 convert): logits + top-2 + compaction + xb -----
__global__ __launch_bounds__(256) void router_kernel(
        const float* __restrict__ x, const float* __restrict__ rW,
        float* __restrict__ logits, int* __restrict__ selpk,
        int* __restrict__ slotpk, int* __restrict__ cnt, int* __restrict__ list,
        unsigned short* __restrict__ xb) {
    __shared__ int se[8];
    __shared__ int sslot[8];
    int wid = threadIdx.x >> 6, lane = threadIdx.x & 63;
    int t = blockIdx.x * 4 + wid;
    const float* xr = x + (size_t)t * D_MODEL;
    unsigned short* xbr = xb + (size_t)t * D_MODEL;
    float a0 = 0.f, a1 = 0.f, a2 = 0.f, a3 = 0.f;
    #pragma unroll
    for (int i = 0; i < 4; ++i) {
        int d4 = lane + i * 64;                 // float4 index within row
        f32x4 xv = *(const f32x4*)&xr[d4 * 4];
        u16x4 bo;
        #pragma unroll
        for (int j = 0; j < 4; ++j) {
            float xj = xv[j];
            f32x4 wv = *(const f32x4*)&rW[(d4 * 4 + j) * 4];
            a0 = __builtin_fmaf(xj, wv[0], a0);
            a1 = __builtin_fmaf(xj, wv[1], a1);
            a2 = __builtin_fmaf(xj, wv[2], a2);
            a3 = __builtin_fmaf(xj, wv[3], a3);
            bo[j] = f2bf(xj);
        }
        *(u16x4*)&xbr[d4 * 4] = bo;
    }
    #pragma unroll
    for (int off = 32; off; off >>= 1) {
        a0 += __shfl_xor(a0, off); a1 += __shfl_xor(a1, off);
        a2 += __shfl_xor(a2, off); a3 += __shfl_xor(a3, off);
    }
    if (lane == 0) {
        float l[4] = {a0, a1, a2, a3};
        logits[t * 4 + 0] = a0; logits[t * 4 + 1] = a1;
        logits[t * 4 + 2] = a2; logits[t * 4 + 3] = a3;
        int e0 = 0; float b = l[0];
        #pragma unroll
        for (int e = 1; e < 4; ++e) if (l[e] > b) { b = l[e]; e0 = e; }
        int e1 = -1; float b2 = -1e30f;
        #pragma unroll
        for (int e = 0; e < 4; ++e) {
            if (e == e0) continue;
            if (l[e] > b2) { b2 = l[e]; e1 = e; }
        }
        se[wid * 2] = e0; se[wid * 2 + 1] = e1;
    }
    __syncthreads();
    if (threadIdx.x == 0) {
        int cnts[4] = {0, 0, 0, 0}, base[4];
        #pragma unroll
        for (int k = 0; k < 8; ++k) cnts[se[k]]++;
        #pragma unroll
        for (int e = 0; e < 4; ++e)
            if (cnts[e]) base[e] = atomicAdd(&cnt[e * 32], cnts[e]);
        int run[4] = {0, 0, 0, 0};
        #pragma unroll
        for (int k = 0; k < 8; ++k) {
            int e = se[k];
            int s = base[e] + run[e]++;
            sslot[k] = s;
            list[e * NTOK + s] = blockIdx.x * 4 + (k >> 1);
        }
    }
    __syncthreads();
    if (lane == 0) {
        selpk[t] = se[wid * 2] | (se[wid * 2 + 1] << 8);
        slotpk[t] = sslot[wid * 2] | (sslot[wid * 2 + 1] << 16);
    }
}

// ---------------- asymmetric-tile 2-barrier GEMM (round-9 proven best) --------
// BM = WM*64, BN = WN*64, WM*WN = 8 waves, per-wave C = 64x64, 48 KiB LDS.
// No min-occupancy launch_bounds (round-8 spill lesson). Simple 2-barrier loop
// (rounds 4/5/6/10/11 all proved every explicit-pipeline variant slower —
// multi-block TLP is what hides staging latency on this structure, m114).
// Quad-XCD swizzle: work W = 4*(D&7) + 32*((D>>3)>>2) + ((D>>3)&3) — bijective
// for nwg%32==0; each XCD runs quads of 4 consecutive W sharing one A-panel.
template<int GELU, int WM, int WN, int GX, int GY>
__global__ __launch_bounds__(512) void gemm_kernel(
        const unsigned short* __restrict__ A, const unsigned short* __restrict__ B,
        const float* __restrict__ bias, int bias_stride, int ldo,
        unsigned short* __restrict__ out,
        const int* __restrict__ cnt, const int* __restrict__ list, int K) {
    constexpr int BM = WM * 64, BN = WN * 64;
    __shared__ unsigned short As[BM * 64];
    __shared__ unsigned short Bs[BN * 64];

    // balanced quad-XCD swizzle (nwg = GX*GY*6, multiple of 32 for both passes)
    const int D = blockIdx.x + GX * (blockIdx.y + GY * blockIdx.z);
    const int tq = D >> 3;
    const int W = ((D & 7) << 2) + ((tq >> 2) << 5) + (tq & 3);
    const int bx = W % GX;
    const int rem = W / GX;
    const int by = rem % GY;
    const int e  = rem / GY;

    const int tid = threadIdx.x, lane = tid & 63, w = tid >> 6;
    int ecnt = NTOK, rowbase;
    if (e < 2) {
        rowbase = e * NTOK + by * BM;
    } else {
        int seg[4], pc[4];
        seg_of(cnt, seg, pc);
        int ev = e - 2;
        ecnt = cnt[ev * 32];
        if (by * BM >= pc[ev]) return;   // before any barrier
        rowbase = seg[ev] + by * BM;
    }
    const int n0 = bx * BN;
    const unsigned short* Be = B + (size_t)e * (D_FF * D_MODEL);

    // per-thread staging sources (pre-swizzled source piece, linear LDS dest);
    // load i covers rows i*64 + w*8 + (lane>>3), piece (lane&7)^(row&7)
    const unsigned short* asrc[WM];
    const unsigned short* bsrc[WN];
    #pragma unroll
    for (int i = 0; i < WM; ++i) {
        int row = i * 64 + w * 8 + (lane >> 3);
        int kc = lane & 7;
        size_t arow;
        if (GELU) {
            int s = by * BM + row;
            if (e < 2) arow = (size_t)s;
            else       arow = (size_t)((s < ecnt) ? list[(e - 2) * NTOK + s] : 0);
        } else {
            arow = (size_t)(rowbase + row);
        }
        asrc[i] = A + arow * K + ((kc ^ (row & 7)) << 3);
    }
    #pragma unroll
    for (int i = 0; i < WN; ++i) {
        int row = i * 64 + w * 8 + (lane >> 3);
        int kc = lane & 7;
        bsrc[i] = Be + (size_t)(n0 + row) * K + ((kc ^ (row & 7)) << 3);
    }

    const int wm = (w / WN) * 64, wn = (w % WN) * 64;
    const int rl = lane & 15, kq = lane >> 4;

    // bias folded into accumulator init (column-only => all 4 C regs equal)
    float bv[4];
    #pragma unroll
    for (int ni = 0; ni < 4; ++ni)
        bv[ni] = bias[(size_t)e * bias_stride + n0 + wn + ni * 16 + rl];

    f32x4 acc[4][4];
    #pragma unroll
    for (int mi = 0; mi < 4; ++mi)
        #pragma unroll
        for (int ni = 0; ni < 4; ++ni) acc[mi][ni] = (f32x4)(bv[ni]);

    for (int kb = 0; kb < K; kb += 64) {
        #pragma unroll
        for (int i = 0; i < WM; ++i)
            gload16(asrc[i] + kb, &As[(i * 8 + w) * 512]);
        #pragma unroll
        for (int i = 0; i < WN; ++i)
            gload16(bsrc[i] + kb, &Bs[(i * 8 + w) * 512]);
        asm volatile("s_waitcnt vmcnt(0)" ::: "memory");
        __syncthreads();
        #pragma unroll
        for (int kk = 0; kk < 2; ++kk) {
            int kof = kk * 32 + kq * 8;
            bf16x8 a[4], b[4];
            #pragma unroll
            for (int mi = 0; mi < 4; ++mi) {
                int r = wm + mi * 16 + rl;
                a[mi] = *(const bf16x8*)&As[r * 64 + (kof ^ ((r & 7) << 3))];
            }
            #pragma unroll
            for (int ni = 0; ni < 4; ++ni) {
                int r = wn + ni * 16 + rl;
                b[ni] = *(const bf16x8*)&Bs[r * 64 + (kof ^ ((r & 7) << 3))];
            }
            #pragma unroll
            for (int mi = 0; mi < 4; ++mi)
                #pragma unroll
                for (int ni = 0; ni < 4; ++ni)
                    acc[mi][ni] = __builtin_amdgcn_mfma_f32_16x16x32_bf16(
                        a[mi], b[ni], acc[mi][ni], 0, 0, 0);
        }
        __syncthreads();
    }

    // epilogue: (gelu) + packed bf16 convert + store
    #pragma unroll
    for (int ni = 0; ni < 4; ++ni) {
        int c = n0 + wn + ni * 16 + rl;
        #pragma unroll
        for (int mi = 0; mi < 4; ++mi) {
            #pragma unroll
            for (int jp = 0; jp < 2; ++jp) {
                float g0 = acc[mi][ni][jp * 2 + 0];
                float g1 = acc[mi][ni][jp * 2 + 1];
                if (GELU) { g0 = gelu_fast(g0); g1 = gelu_fast(g1); }
                unsigned pk;
                asm("v_cvt_pk_bf16_f32 %0, %1, %2" : "=v"(pk) : "v"(g0), "v"(g1));
                int r = wm + mi * 16 + kq * 4 + jp * 2;
                unsigned short* p = out + (size_t)(rowbase + r) * ldo + c;
                p[0]   = (unsigned short)pk;
                p[ldo] = (unsigned short)(pk >> 16);
            }
        }
    }
}

// ---------------- pass3: gather 4 bf16 rows, /4, LayerNorm ----------------
__global__ __launch_bounds__(256) void pass3_kernel(
        const unsigned short* __restrict__ oslab, const int* __restrict__ selpk,
        const int* __restrict__ slotpk, const int* __restrict__ cnt,
        const float* __restrict__ gamma, const float* __restrict__ beta,
        float* __restrict__ out) {
    int t = blockIdx.x;
    int seg[4], pc[4];
    seg_of(cnt, seg, pc);
    int sp = selpk[t], sl = slotpk[t];
    int e0 = sp & 0xff, e1 = (sp >> 8) & 0xff;
    int s0 = sl & 0xffff, s1 = (sl >> 16) & 0xffff;
    const unsigned short* p0 = oslab + (size_t)t * D_MODEL;
    const unsigned short* p1 = oslab + (size_t)(NTOK + t) * D_MODEL;
    const unsigned short* p2 = oslab + (size_t)(seg[e0] + s0) * D_MODEL;
    const unsigned short* p3 = oslab + (size_t)(seg[e1] + s1) * D_MODEL;
    float c[4];
    float sum = 0.f, sq = 0.f;
    #pragma unroll
    for (int i = 0; i < 4; ++i) {
        int d = threadIdx.x + i * 256;
        float v = (b2f(p0[d]) + b2f(p1[d]) + b2f(p2[d]) + b2f(p3[d])) * 0.25f;
        c[i] = v; sum += v; sq += v * v;
    }
    #pragma unroll
    for (int off = 32; off; off >>= 1) {
        sum += __shfl_xor(sum, off);
        sq  += __shfl_xor(sq, off);
    }
    __shared__ float red[8];
    int lane = threadIdx.x & 63, wid = threadIdx.x >> 6;
    if (lane == 0) { red[wid] = sum; red[4 + wid] = sq; }
    __syncthreads();
    sum = red[0] + red[1] + red[2] + red[3];
    sq  = red[4] + red[5] + red[6] + red[7];
    float mean = sum * (1.0f / 1024.0f);
    float var = sq * (1.0f / 1024.0f) - mean * mean;
    float inv = rsqrtf(var + LN_EPS);
    #pragma unroll
    for (int i = 0; i < 4; ++i) {
        int d = threadIdx.x + i * 256;
        out[(size_t)t * D_MODEL + d] = (c[i] - mean) * inv * gamma[d] + beta[d];
    }
}

extern "C" void kernel_launch(void* const* d_in, const int* in_sizes, int n_in,
                              void* d_out, int out_size, void* d_ws, size_t ws_size,
                              hipStream_t stream) {
    const float* x   = (const float*)d_in[0];
    const float* rW  = (const float*)d_in[1];
    const float* W1  = (const float*)d_in[2];
    const float* b1  = (const float*)d_in[3];
    const float* W2  = (const float*)d_in[4];
    const float* b2  = (const float*)d_in[5];
    const float* gam = (const float*)d_in[6];
    const float* bet = (const float*)d_in[7];
    float* out = (float*)d_out;
    float* logits = out + (size_t)NTOK * D_MODEL;

    char* ws = (char*)d_ws;
    int* cnt    = (int*)ws;                     // 4 counters, 128B apart
    int* selpk  = (int*)(ws + 0x1000);
    int* slotpk = (int*)(ws + 0x6000);
    int* list   = (int*)(ws + 0xB000);          // 4*4096*4 = 64KB
    unsigned short* xb    = (unsigned short*)(ws + 0x20000);    // 8 MiB
    unsigned short* W1t   = (unsigned short*)(ws + 0x820000);   // 48 MiB
    unsigned short* W2t   = (unsigned short*)(ws + 0x3820000);  // 48 MiB
    unsigned short* oslab = (unsigned short*)(ws + 0x6820000);  // 17408*1024*2 = 34 MiB
    unsigned short* h     = (unsigned short*)(ws + 0x8A20000);  // 17408*4096*2 = 136 MiB
    // total ≈ 287.4 MB (proven available)

    hipMemsetAsync(cnt, 0, 512, stream);
    router_kernel<<<NTOK / 4, 256, 0, stream>>>(x, rW, logits, selpk, slotpk, cnt, list, xb);
    transpose_kernel<<<dim3(D_FF / 64, D_MODEL / 64, 6), 256, 0, stream>>>(W1, W1t, D_MODEL, D_FF);
    transpose_kernel<<<dim3(D_MODEL / 64, D_FF / 64, 6), 256, 0, stream>>>(W2, W2t, D_FF, D_MODEL);

    // pass1: h = gelu(x @ W1^T + b1)   BM=256 (halve W1t re-reads), BN=128
    // grid (32, 16, 6) => nwg 3072 (mult of 32)
    gemm_kernel<1, 4, 2, 32, 16><<<dim3(32, 16, 6), 512, 0, stream>>>(
        xb, W1t, b1, D_FF, D_FF, h, cnt, list, D_MODEL);
    // pass2: oslab = h @ W2^T + b2     BM=128, BN=256 (halve h re-reads)
    // grid (4, 32, 6) => nwg 768 (mult of 32)
    gemm_kernel<0, 2, 4, 4, 32><<<dim3(4, 32, 6), 512, 0, stream>>>(
        h, W2t, b2, D_MODEL, D_MODEL, oslab, cnt, list, D_FF);

    pass3_kernel<<<NTOK, 256, 0, stream>>>(oslab, selpk, slotpk, cnt, gam, bet, out);
}